// Round 2
// baseline (2135.917 us; speedup 1.0000x reference)
//
#include <hip/hip_runtime.h>

#define EXPERTS 8
#define HID 2048
#define INTER 4096
#define BTOK 2048
#define NASSIGN 4096   // BTOK * TOPK

typedef float f32x4 __attribute__((ext_vector_type(4)));
typedef __bf16 bf16x8 __attribute__((ext_vector_type(8)));
typedef unsigned short ushortx8 __attribute__((ext_vector_type(8)));

__device__ __forceinline__ float bf2f(unsigned short u) {
  union { unsigned int u32; float f; } v; v.u32 = ((unsigned int)u) << 16; return v.f;
}
__device__ __forceinline__ unsigned short f2bf(float f) {
  union { float f; unsigned int u; } v; v.f = f;
  unsigned int r = v.u + 0x7fffu + ((v.u >> 16) & 1u);   // RNE
  return (unsigned short)(r >> 16);
}

// ---------------- workspace layout (bytes) ----------------
#define W1T_OFF  0ULL                                   // [E][INTER][HID] bf16 = 128 MiB
#define W3T_OFF  (W1T_OFF + 134217728ULL)               // 128 MiB
#define W2T_OFF  (W3T_OFF + 134217728ULL)               // [E][HID][INTER] bf16 = 128 MiB
#define XB_OFF   (W2T_OFF + 134217728ULL)               // [BTOK][HID] bf16 = 8 MiB
#define G1_OFF   (XB_OFF  + 8388608ULL)                 // [NASSIGN][INTER] bf16 = 32 MiB
#define GB_OFF   (G1_OFF  + 33554432ULL)                // 32 MiB
#define Y_OFF    (GB_OFF  + 33554432ULL)                // [NASSIGN][HID] f32 = 32 MiB
#define ROWS_OFF (Y_OFF   + 33554432ULL)                // 4096 int
#define OFFS_OFF (ROWS_OFF + 16384ULL)                  // 9 int

// ---------------- routing: deterministic counting sort ----------------
__global__ void routing_kernel(const int* __restrict__ eraw,
                               int* __restrict__ rows, int* __restrict__ offs_g)
{
  __shared__ int cnt[256 * 8];
  __shared__ int offs_s[9];
  __shared__ int found_odd;   // nonzero odd int32 -> data is int32-packed
  const int tid = threadIdx.x;
  if (tid == 0) found_odd = 0;
  __syncthreads();
  // probe layout: if expert_indices is int64, every odd int32 (high word) is 0.
  int any = 0;
  for (int j = 0; j < 8; ++j) {
    int a = tid * 8 + j;            // a < 2048: odd index < 4096, safe in both layouts
    any |= (eraw[2 * a + 1] != 0);
  }
  if (any) atomicOr(&found_odd, 1);
  __syncthreads();
  const bool i64 = (found_odd == 0);

  // local counts over 16 assignments per thread
  int lc[8];
  for (int e = 0; e < 8; ++e) lc[e] = 0;
  for (int j = 0; j < 16; ++j) {
    int a = tid * 16 + j;
    int e = i64 ? eraw[2 * a] : eraw[a];
    lc[e]++;
  }
  for (int e = 0; e < 8; ++e) cnt[tid * 8 + e] = lc[e];
  __syncthreads();
  // exclusive scan over threads, per expert
  __shared__ int tot[8];
  if (tid < 8) {
    int run = 0;
    for (int t = 0; t < 256; ++t) {
      int v = cnt[t * 8 + tid];
      cnt[t * 8 + tid] = run;
      run += v;
    }
    tot[tid] = run;
  }
  __syncthreads();
  if (tid == 0) {
    int o = 0;
    for (int e = 0; e < 8; ++e) { offs_s[e] = o; o += tot[e]; }
    offs_s[8] = o;  // == 4096
  }
  __syncthreads();
  if (tid < 9) offs_g[tid] = offs_s[tid];
  // scatter in deterministic (thread, j) order
  int lc2[8];
  for (int e = 0; e < 8; ++e) lc2[e] = 0;
  for (int j = 0; j < 16; ++j) {
    int a = tid * 16 + j;
    int e = i64 ? eraw[2 * a] : eraw[a];
    rows[offs_s[e] + cnt[tid * 8 + e] + lc2[e]] = a;
    lc2[e]++;
  }
}

// ---------------- x: f32 -> bf16 ----------------
__global__ void convert_x_kernel(const float* __restrict__ x, unsigned short* __restrict__ xb)
{
  long idx = (long)blockIdx.x * 256 + threadIdx.x;   // 1M threads, 4 elems each
  float4 v = *(const float4*)&x[idx * 4];
  unsigned int lo = (unsigned int)f2bf(v.x) | ((unsigned int)f2bf(v.y) << 16);
  unsigned int hi = (unsigned int)f2bf(v.z) | ((unsigned int)f2bf(v.w) << 16);
  uint2 p; p.x = lo; p.y = hi;
  *(uint2*)&xb[idx * 4] = p;
}

// ---------------- weights: f32 [R][C] -> bf16 [C][R] ----------------
__global__ void transpose_convert_kernel(const float* __restrict__ w1,
                                         const float* __restrict__ w2,
                                         const float* __restrict__ w3,
                                         unsigned short* __restrict__ w1t,
                                         unsigned short* __restrict__ w2t,
                                         unsigned short* __restrict__ w3t)
{
  const int m = blockIdx.z;
  const float* src; unsigned short* dst; int R, C;
  if (m < 8)       { src = w1 + (long)m * HID * INTER;        dst = w1t + (long)m * INTER * HID;        R = HID;   C = INTER; }
  else if (m < 16) { src = w3 + (long)(m - 8) * HID * INTER;  dst = w3t + (long)(m - 8) * INTER * HID;  R = HID;   C = INTER; }
  else             { src = w2 + (long)(m - 16) * INTER * HID; dst = w2t + (long)(m - 16) * HID * INTER; R = INTER; C = HID;  }
  const int rt = blockIdx.y, ct = blockIdx.x;
  if (rt * 64 >= R || ct * 64 >= C) return;

  __shared__ float tile[64][65];
  const int tid = threadIdx.x;
  #pragma unroll
  for (int p = 0; p < 4; ++p) {
    int i4 = p * 256 + tid;                 // 1024 float4 = 4096 floats
    int r = i4 >> 4, c4 = (i4 & 15) << 2;
    float4 v = *(const float4*)&src[(long)(rt * 64 + r) * C + ct * 64 + c4];
    tile[r][c4 + 0] = v.x; tile[r][c4 + 1] = v.y;
    tile[r][c4 + 2] = v.z; tile[r][c4 + 3] = v.w;
  }
  __syncthreads();
  #pragma unroll
  for (int p = 0; p < 8; ++p) {
    int pi = p * 256 + tid;                 // 2048 pairs
    int cc = pi >> 5, rp = pi & 31;
    float f0 = tile[2 * rp][cc], f1 = tile[2 * rp + 1][cc];
    unsigned int u = (unsigned int)f2bf(f0) | ((unsigned int)f2bf(f1) << 16);
    long o = (long)(ct * 64 + cc) * R + rt * 64 + 2 * rp;
    *(unsigned int*)&dst[o] = u;
  }
}

// ---------------- grouped GEMM (m97 structure) ----------------
// MODE 0: G1 = A(xb rows) * Bt(w1t)       -> bf16 plain store
// MODE 1: Gb = silu(G1) * (A * Bt(w3t))   -> bf16 store
// MODE 2: Y[rows[r]] = A(Gb) * Bt(w2t)    -> f32 scatter store
template<int MODE>
__global__ __launch_bounds__(256, 2) void gemm_kernel(
    const unsigned short* __restrict__ A,
    const unsigned short* __restrict__ Bt,
    const unsigned short* __restrict__ G1in,
    void* __restrict__ OutP,
    const int* __restrict__ rows,
    const int* __restrict__ offs,
    const int N, const int Kd)
{
  const int e   = blockIdx.z;
  const int off = offs[e];
  const int cnt = offs[e + 1] - off;
  const int mt  = blockIdx.x;
  if (mt * 128 >= cnt) return;
  const int nt  = blockIdx.y;

  __shared__ __align__(16) unsigned short As[128 * 32];
  __shared__ __align__(16) unsigned short Bs[128 * 32];

  const int tid  = threadIdx.x;
  const int lane = tid & 63;
  const int wave = tid >> 6;
  const int wr = wave >> 1, wc = wave & 1;

  const unsigned short* aptr[2];
  const unsigned short* bptr[2];
  const unsigned short* Bte = Bt + (long)e * (long)N * (long)Kd;
  #pragma unroll
  for (int c = 0; c < 2; ++c) {
    int idx = tid + c * 256;
    int row = idx >> 2, seg = idx & 3;
    int r  = off + mt * 128 + row;
    int rv = (r < off + cnt) ? r : (off + cnt - 1);
    long arow;
    if (MODE == 2) arow = rv;               // Gb is compacted by routed row
    else           arow = (rows[rv] >> 1);  // token id
    aptr[c] = A   + arow * (long)Kd + seg * 8;
    bptr[c] = Bte + (long)(nt * 128 + row) * (long)Kd + seg * 8;
  }

  f32x4 acc[4][4];
  #pragma unroll
  for (int i = 0; i < 4; ++i)
    #pragma unroll
    for (int j = 0; j < 4; ++j)
      acc[i][j] = (f32x4)0.0f;

  for (int k0 = 0; k0 < Kd; k0 += 32) {
    __syncthreads();
    #pragma unroll
    for (int c = 0; c < 2; ++c) {
      __builtin_amdgcn_global_load_lds(
          (const __attribute__((address_space(1))) unsigned int*)(aptr[c] + k0),
          (__attribute__((address_space(3))) unsigned int*)(As + (c * 256 + wave * 64) * 8),
          16, 0, 0);
      __builtin_amdgcn_global_load_lds(
          (const __attribute__((address_space(1))) unsigned int*)(bptr[c] + k0),
          (__attribute__((address_space(3))) unsigned int*)(Bs + (c * 256 + wave * 64) * 8),
          16, 0, 0);
    }
    __syncthreads();

    bf16x8 af[4], bfr[4];
    #pragma unroll
    for (int f = 0; f < 4; ++f) {
      int ar = wr * 64 + f * 16 + (lane & 15);
      af[f]  = __builtin_bit_cast(bf16x8, *(const ushortx8*)&As[ar * 32 + (lane >> 4) * 8]);
      int br = wc * 64 + f * 16 + (lane & 15);
      bfr[f] = __builtin_bit_cast(bf16x8, *(const ushortx8*)&Bs[br * 32 + (lane >> 4) * 8]);
    }
    #pragma unroll
    for (int i = 0; i < 4; ++i)
      #pragma unroll
      for (int j = 0; j < 4; ++j)
        acc[i][j] = __builtin_amdgcn_mfma_f32_16x16x32_bf16(af[i], bfr[j], acc[i][j], 0, 0, 0);
  }

  // epilogue: C/D layout col = lane&15, row = (lane>>4)*4 + q  [m89-verified]
  const int grb  = off + mt * 128 + wr * 64;
  const int gcb  = nt * 128 + wc * 64;
  const int rtop = off + cnt;
  #pragma unroll
  for (int i = 0; i < 4; ++i) {
    #pragma unroll
    for (int j = 0; j < 4; ++j) {
      int gc = gcb + j * 16 + (lane & 15);
      #pragma unroll
      for (int q = 0; q < 4; ++q) {
        int gr = grb + i * 16 + (lane >> 4) * 4 + q;
        if (gr < rtop) {
          float v = acc[i][j][q];
          if (MODE == 0) {
            ((unsigned short*)OutP)[(long)gr * N + gc] = f2bf(v);
          } else if (MODE == 1) {
            float g = bf2f(G1in[(long)gr * N + gc]);
            float s = g / (1.0f + __expf(-g));   // silu(gate)
            ((unsigned short*)OutP)[(long)gr * N + gc] = f2bf(s * v);
          } else {
            int a = rows[gr];
            ((float*)OutP)[(long)a * N + gc] = v;
          }
        }
      }
    }
  }
}

// ---------------- combine: out[t] = ew0*Y[2t] + ew1*Y[2t+1] ----------------
__global__ void combine_kernel(const float* __restrict__ Y,
                               const float* __restrict__ ew,
                               float* __restrict__ out)
{
  int idx = blockIdx.x * 256 + threadIdx.x;   // 1M threads, 4 h each
  int t = idx >> 9;
  int h = (idx & 511) * 4;
  float w0 = ew[2 * t], w1 = ew[2 * t + 1];
  float4 y0 = *(const float4*)&Y[(long)(2 * t) * HID + h];
  float4 y1 = *(const float4*)&Y[(long)(2 * t + 1) * HID + h];
  float4 o;
  o.x = w0 * y0.x + w1 * y1.x;
  o.y = w0 * y0.y + w1 * y1.y;
  o.z = w0 * y0.z + w1 * y1.z;
  o.w = w0 * y0.w + w1 * y1.w;
  *(float4*)&out[(long)t * HID + h] = o;
}

extern "C" void kernel_launch(void* const* d_in, const int* in_sizes, int n_in,
                              void* d_out, int out_size, void* d_ws, size_t ws_size,
                              hipStream_t stream) {
  const float* x   = (const float*)d_in[0];
  const int*   eix = (const int*)d_in[1];
  const float* ew  = (const float*)d_in[2];
  const float* w1  = (const float*)d_in[3];
  const float* w2  = (const float*)d_in[4];
  const float* w3  = (const float*)d_in[5];
  float* out = (float*)d_out;

  char* ws = (char*)d_ws;
  unsigned short* w1t = (unsigned short*)(ws + W1T_OFF);
  unsigned short* w3t = (unsigned short*)(ws + W3T_OFF);
  unsigned short* w2t = (unsigned short*)(ws + W2T_OFF);
  unsigned short* xb  = (unsigned short*)(ws + XB_OFF);
  unsigned short* g1  = (unsigned short*)(ws + G1_OFF);
  unsigned short* gb  = (unsigned short*)(ws + GB_OFF);
  float*          y   = (float*)(ws + Y_OFF);
  int*            rows = (int*)(ws + ROWS_OFF);
  int*            offs = (int*)(ws + OFFS_OFF);

  routing_kernel<<<1, 256, 0, stream>>>(eix, rows, offs);
  convert_x_kernel<<<4096, 256, 0, stream>>>(x, xb);
  transpose_convert_kernel<<<dim3(64, 64, 24), 256, 0, stream>>>(w1, w2, w3, w1t, w2t, w3t);
  // gate: G1 = X * W1^T
  gemm_kernel<0><<<dim3(32, INTER / 128, EXPERTS), 256, 0, stream>>>(
      xb, w1t, nullptr, (void*)g1, rows, offs, INTER, HID);
  // up + fuse: Gb = silu(G1) * (X * W3^T)
  gemm_kernel<1><<<dim3(32, INTER / 128, EXPERTS), 256, 0, stream>>>(
      xb, w3t, g1, (void*)gb, rows, offs, INTER, HID);
  // down: Y[a] = Gb * W2^T
  gemm_kernel<2><<<dim3(32, HID / 128, EXPERTS), 256, 0, stream>>>(
      gb, w2t, nullptr, (void*)y, rows, offs, HID, INTER);
  combine_kernel<<<4096, 256, 0, stream>>>(y, ew, out);
}

// Round 5
// 603.784 us; speedup vs baseline: 3.5376x; 3.5376x over previous
//
#include <hip/hip_runtime.h>

#define EXPERTS 8
#define HID 2048
#define INTER 4096
#define BTOK 2048
#define NASSIGN 4096   // BTOK * TOPK
#define NTSLOTS 40     // max sum_e ceil(cnt_e/128) = 32+7

typedef float f32x4 __attribute__((ext_vector_type(4)));
typedef __bf16 bf16x8 __attribute__((ext_vector_type(8)));
typedef unsigned short ushortx8 __attribute__((ext_vector_type(8)));

__device__ __forceinline__ float bf2f(unsigned short u) {
  union { unsigned int u32; float f; } v; v.u32 = ((unsigned int)u) << 16; return v.f;
}
__device__ __forceinline__ unsigned short f2bf(float f) {
  union { float f; unsigned int u; } v; v.f = f;
  unsigned int r = v.u + 0x7fffu + ((v.u >> 16) & 1u);   // RNE
  return (unsigned short)(r >> 16);
}

// ---------------- workspace layout (bytes) ----------------
#define W1T_OFF  0ULL                                   // [E][INTER][HID] bf16 = 128 MiB
#define W3T_OFF  (W1T_OFF + 134217728ULL)               // 128 MiB
#define W2T_OFF  (W3T_OFF + 134217728ULL)               // [E][HID][INTER] bf16 = 128 MiB
#define XB_OFF   (W2T_OFF + 134217728ULL)               // [BTOK][HID] bf16 = 8 MiB
#define GB_OFF   (XB_OFF  + 8388608ULL)                 // [NASSIGN][INTER] bf16 = 32 MiB
#define Y_OFF    (GB_OFF  + 33554432ULL)                // [NASSIGN][HID] f32 = 32 MiB
#define ROWS_OFF (Y_OFF   + 33554432ULL)                // 4096 int
#define OFFS_OFF (ROWS_OFF + 16384ULL)                  // 9 int (padded 64B)
#define TILE_OFF (OFFS_OFF + 64ULL)                     // 40 int

// ---------------- routing: deterministic counting sort + tile table ----------------
__global__ void routing_kernel(const int* __restrict__ eraw,
                               int* __restrict__ rows, int* __restrict__ offs_g,
                               int* __restrict__ tiles)
{
  __shared__ int cnt[256 * 8];
  __shared__ int offs_s[9];
  __shared__ int tot[8];
  __shared__ int found_odd;   // nonzero odd int32 -> data is int32-packed
  const int tid = threadIdx.x;
  if (tid == 0) found_odd = 0;
  __syncthreads();
  // probe layout: if expert_indices is int64, every odd int32 (high word) is 0.
  int any = 0;
  for (int j = 0; j < 8; ++j) {
    int a = tid * 8 + j;            // a < 2048: odd index < 4096, safe in both layouts
    any |= (eraw[2 * a + 1] != 0);
  }
  if (any) atomicOr(&found_odd, 1);
  __syncthreads();
  const bool i64 = (found_odd == 0);

  int lc[8];
  for (int e = 0; e < 8; ++e) lc[e] = 0;
  for (int j = 0; j < 16; ++j) {
    int a = tid * 16 + j;
    int e = i64 ? eraw[2 * a] : eraw[a];
    lc[e]++;
  }
  for (int e = 0; e < 8; ++e) cnt[tid * 8 + e] = lc[e];
  __syncthreads();
  if (tid < 8) {
    int run = 0;
    for (int t = 0; t < 256; ++t) {
      int v = cnt[t * 8 + tid];
      cnt[t * 8 + tid] = run;
      run += v;
    }
    tot[tid] = run;
  }
  __syncthreads();
  if (tid == 0) {
    int o = 0;
    for (int e = 0; e < 8; ++e) { offs_s[e] = o; o += tot[e]; }
    offs_s[8] = o;  // == 4096
    // tile table: (expert, mt) pairs, BM=128
    int s = 0;
    for (int e = 0; e < 8; ++e) {
      int nmt = (tot[e] + 127) >> 7;
      for (int m = 0; m < nmt; ++m) tiles[s++] = (e << 16) | m;
    }
    for (; s < NTSLOTS; ++s) tiles[s] = -1;
  }
  __syncthreads();
  if (tid < 9) offs_g[tid] = offs_s[tid];
  int lc2[8];
  for (int e = 0; e < 8; ++e) lc2[e] = 0;
  for (int j = 0; j < 16; ++j) {
    int a = tid * 16 + j;
    int e = i64 ? eraw[2 * a] : eraw[a];
    rows[offs_s[e] + cnt[tid * 8 + e] + lc2[e]] = a;
    lc2[e]++;
  }
}

// ---------------- x: f32 -> bf16 ----------------
__global__ void convert_x_kernel(const float* __restrict__ x, unsigned short* __restrict__ xb)
{
  long idx = (long)blockIdx.x * 256 + threadIdx.x;
  float4 v = *(const float4*)&x[idx * 4];
  unsigned int lo = (unsigned int)f2bf(v.x) | ((unsigned int)f2bf(v.y) << 16);
  unsigned int hi = (unsigned int)f2bf(v.z) | ((unsigned int)f2bf(v.w) << 16);
  uint2 p; p.x = lo; p.y = hi;
  *(uint2*)&xb[idx * 4] = p;
}

// ---------------- weights: f32 [R][C] -> bf16 [C][R] ----------------
__global__ void transpose_convert_kernel(const float* __restrict__ w1,
                                         const float* __restrict__ w2,
                                         const float* __restrict__ w3,
                                         unsigned short* __restrict__ w1t,
                                         unsigned short* __restrict__ w2t,
                                         unsigned short* __restrict__ w3t)
{
  const int m = blockIdx.z;
  const float* src; unsigned short* dst; int R, C;
  if (m < 8)       { src = w1 + (long)m * HID * INTER;        dst = w1t + (long)m * INTER * HID;        R = HID;   C = INTER; }
  else if (m < 16) { src = w3 + (long)(m - 8) * HID * INTER;  dst = w3t + (long)(m - 8) * INTER * HID;  R = HID;   C = INTER; }
  else             { src = w2 + (long)(m - 16) * INTER * HID; dst = w2t + (long)(m - 16) * HID * INTER; R = INTER; C = HID;  }
  const int rt = blockIdx.y, ct = blockIdx.x;
  if (rt * 64 >= R || ct * 64 >= C) return;

  __shared__ float tile[64][65];
  const int tid = threadIdx.x;
  #pragma unroll
  for (int p = 0; p < 4; ++p) {
    int i4 = p * 256 + tid;
    int r = i4 >> 4, c4 = (i4 & 15) << 2;
    float4 v = *(const float4*)&src[(long)(rt * 64 + r) * C + ct * 64 + c4];
    tile[r][c4 + 0] = v.x; tile[r][c4 + 1] = v.y;
    tile[r][c4 + 2] = v.z; tile[r][c4 + 3] = v.w;
  }
  __syncthreads();
  #pragma unroll
  for (int p = 0; p < 8; ++p) {
    int pi = p * 256 + tid;
    int cc = pi >> 5, rp = pi & 31;
    float f0 = tile[2 * rp][cc], f1 = tile[2 * rp + 1][cc];
    unsigned int u = (unsigned int)f2bf(f0) | ((unsigned int)f2bf(f1) << 16);
    long o = (long)(ct * 64 + cc) * R + rt * 64 + 2 * rp;
    *(unsigned int*)&dst[o] = u;
  }
}

// ---------------- fused gate+up grouped GEMM, 2-phase pipeline ----------------
// Gb[gr] = silu(X[tok]·W1e^T) * (X[tok]·W3e^T), BM=128 BN=64 BK=32
__global__ __launch_bounds__(256, 3) void gemm_gateup(
    const unsigned short* __restrict__ xb,
    const unsigned short* __restrict__ w1t,
    const unsigned short* __restrict__ w3t,
    unsigned short* __restrict__ gb,
    const int* __restrict__ rows,
    const int* __restrict__ offs,
    const int* __restrict__ tiles)
{
  const int te = tiles[blockIdx.y];
  if (te < 0) return;
  const int e  = te >> 16, mt = te & 0xffff;
  const int off = offs[e];
  const int cnt = offs[e + 1] - off;
  const int nt  = blockIdx.x;                 // 64 N-tiles of 64 over INTER

  __shared__ __align__(16) unsigned short As[2][128 * 32];
  __shared__ __align__(16) unsigned short B1s[2][64 * 32];
  __shared__ __align__(16) unsigned short B3s[2][64 * 32];

  const int tid  = threadIdx.x;
  const int lane = tid & 63;
  const int wave = tid >> 6;
  const int wr = wave >> 1, wc = wave & 1;

  const unsigned short* aptr[2];
  #pragma unroll
  for (int c = 0; c < 2; ++c) {
    int idx = tid + c * 256;
    int row = idx >> 2, seg = idx & 3;
    int r  = off + mt * 128 + row;
    int rv = (r < off + cnt) ? r : (off + cnt - 1);
    long tok = rows[rv] >> 1;
    aptr[c] = xb + tok * HID + seg * 8;
  }
  const unsigned short* b1p;
  const unsigned short* b3p;
  {
    int row = tid >> 2, seg = tid & 3;
    b1p = w1t + ((long)e * INTER + nt * 64 + row) * HID + seg * 8;
    b3p = w3t + ((long)e * INTER + nt * 64 + row) * HID + seg * 8;
  }

  auto STAGE = [&](int buf, int k0) {
    #pragma unroll
    for (int c = 0; c < 2; ++c)
      __builtin_amdgcn_global_load_lds(
          (const __attribute__((address_space(1))) unsigned int*)(aptr[c] + k0),
          (__attribute__((address_space(3))) unsigned int*)(&As[buf][(c * 256 + wave * 64) * 8]),
          16, 0, 0);
    __builtin_amdgcn_global_load_lds(
        (const __attribute__((address_space(1))) unsigned int*)(b1p + k0),
        (__attribute__((address_space(3))) unsigned int*)(&B1s[buf][wave * 64 * 8]),
        16, 0, 0);
    __builtin_amdgcn_global_load_lds(
        (const __attribute__((address_space(1))) unsigned int*)(b3p + k0),
        (__attribute__((address_space(3))) unsigned int*)(&B3s[buf][wave * 64 * 8]),
        16, 0, 0);
  };

  f32x4 acc1[4][2], acc3[4][2];
  #pragma unroll
  for (int i = 0; i < 4; ++i)
    #pragma unroll
    for (int j = 0; j < 2; ++j) { acc1[i][j] = (f32x4)0.0f; acc3[i][j] = (f32x4)0.0f; }

  STAGE(0, 0);
  __syncthreads();
  const int NIT = HID / 32;   // 64
  for (int t = 0; t < NIT; ++t) {
    const int cur = t & 1;
    if (t + 1 < NIT) STAGE(cur ^ 1, (t + 1) * 32);
    const int koff = (lane >> 4) * 8;
    bf16x8 af[4], b1f[2], b3f[2];
    #pragma unroll
    for (int f = 0; f < 4; ++f)
      af[f] = __builtin_bit_cast(bf16x8, *(const ushortx8*)&As[cur][(wr * 64 + f * 16 + (lane & 15)) * 32 + koff]);
    #pragma unroll
    for (int j = 0; j < 2; ++j) {
      b1f[j] = __builtin_bit_cast(bf16x8, *(const ushortx8*)&B1s[cur][(wc * 32 + j * 16 + (lane & 15)) * 32 + koff]);
      b3f[j] = __builtin_bit_cast(bf16x8, *(const ushortx8*)&B3s[cur][(wc * 32 + j * 16 + (lane & 15)) * 32 + koff]);
    }
    #pragma unroll
    for (int i = 0; i < 4; ++i)
      #pragma unroll
      for (int j = 0; j < 2; ++j) {
        acc1[i][j] = __builtin_amdgcn_mfma_f32_16x16x32_bf16(af[i], b1f[j], acc1[i][j], 0, 0, 0);
        acc3[i][j] = __builtin_amdgcn_mfma_f32_16x16x32_bf16(af[i], b3f[j], acc3[i][j], 0, 0, 0);
      }
    __syncthreads();
  }

  const int rtop = off + cnt;
  const int grb  = off + mt * 128 + wr * 64;
  const int gcb  = nt * 64 + wc * 32;
  #pragma unroll
  for (int i = 0; i < 4; ++i) {
    #pragma unroll
    for (int j = 0; j < 2; ++j) {
      int gc = gcb + j * 16 + (lane & 15);
      #pragma unroll
      for (int q = 0; q < 4; ++q) {
        int gr = grb + i * 16 + (lane >> 4) * 4 + q;
        if (gr < rtop) {
          float g = acc1[i][j][q];
          float u = acc3[i][j][q];
          float s = g / (1.0f + __expf(-g));
          gb[(long)gr * INTER + gc] = f2bf(s * u);
        }
      }
    }
  }
}

// ---------------- down grouped GEMM, 2-phase pipeline ----------------
// Y[rows[gr]] = Gb[gr] · W2e^T, BM=128 BN=64 BK=32, K=INTER
__global__ __launch_bounds__(256, 4) void gemm_down(
    const unsigned short* __restrict__ gbin,
    const unsigned short* __restrict__ w2t,
    float* __restrict__ y,
    const int* __restrict__ rows,
    const int* __restrict__ offs,
    const int* __restrict__ tiles)
{
  const int te = tiles[blockIdx.y];
  if (te < 0) return;
  const int e  = te >> 16, mt = te & 0xffff;
  const int off = offs[e];
  const int cnt = offs[e + 1] - off;
  const int nt  = blockIdx.x;                 // 32 N-tiles of 64 over HID

  __shared__ __align__(16) unsigned short As[2][128 * 32];
  __shared__ __align__(16) unsigned short Bs[2][64 * 32];

  const int tid  = threadIdx.x;
  const int lane = tid & 63;
  const int wave = tid >> 6;
  const int wr = wave >> 1, wc = wave & 1;

  const unsigned short* aptr[2];
  #pragma unroll
  for (int c = 0; c < 2; ++c) {
    int idx = tid + c * 256;
    int row = idx >> 2, seg = idx & 3;
    int r  = off + mt * 128 + row;
    int rv = (r < off + cnt) ? r : (off + cnt - 1);
    aptr[c] = gbin + (long)rv * INTER + seg * 8;
  }
  const unsigned short* bp;
  {
    int row = tid >> 2, seg = tid & 3;
    bp = w2t + ((long)e * HID + nt * 64 + row) * INTER + seg * 8;
  }

  auto STAGE = [&](int buf, int k0) {
    #pragma unroll
    for (int c = 0; c < 2; ++c)
      __builtin_amdgcn_global_load_lds(
          (const __attribute__((address_space(1))) unsigned int*)(aptr[c] + k0),
          (__attribute__((address_space(3))) unsigned int*)(&As[buf][(c * 256 + wave * 64) * 8]),
          16, 0, 0);
    __builtin_amdgcn_global_load_lds(
        (const __attribute__((address_space(1))) unsigned int*)(bp + k0),
        (__attribute__((address_space(3))) unsigned int*)(&Bs[buf][wave * 64 * 8]),
        16, 0, 0);
  };

  f32x4 acc[4][2];
  #pragma unroll
  for (int i = 0; i < 4; ++i)
    #pragma unroll
    for (int j = 0; j < 2; ++j) acc[i][j] = (f32x4)0.0f;

  STAGE(0, 0);
  __syncthreads();
  const int NIT = INTER / 32;   // 128
  for (int t = 0; t < NIT; ++t) {
    const int cur = t & 1;
    if (t + 1 < NIT) STAGE(cur ^ 1, (t + 1) * 32);
    const int koff = (lane >> 4) * 8;
    bf16x8 af[4], bf[2];
    #pragma unroll
    for (int f = 0; f < 4; ++f)
      af[f] = __builtin_bit_cast(bf16x8, *(const ushortx8*)&As[cur][(wr * 64 + f * 16 + (lane & 15)) * 32 + koff]);
    #pragma unroll
    for (int j = 0; j < 2; ++j)
      bf[j] = __builtin_bit_cast(bf16x8, *(const ushortx8*)&Bs[cur][(wc * 32 + j * 16 + (lane & 15)) * 32 + koff]);
    #pragma unroll
    for (int i = 0; i < 4; ++i)
      #pragma unroll
      for (int j = 0; j < 2; ++j)
        acc[i][j] = __builtin_amdgcn_mfma_f32_16x16x32_bf16(af[i], bf[j], acc[i][j], 0, 0, 0);
    __syncthreads();
  }

  const int rtop = off + cnt;
  const int grb  = off + mt * 128 + wr * 64;
  const int gcb  = nt * 64 + wc * 32;
  #pragma unroll
  for (int i = 0; i < 4; ++i) {
    #pragma unroll
    for (int j = 0; j < 2; ++j) {
      int gc = gcb + j * 16 + (lane & 15);
      #pragma unroll
      for (int q = 0; q < 4; ++q) {
        int gr = grb + i * 16 + (lane >> 4) * 4 + q;
        if (gr < rtop) {
          int a = rows[gr];
          y[(long)a * HID + gc] = acc[i][j][q];
        }
      }
    }
  }
}

// ---------------- combine: out[t] = ew0*Y[2t] + ew1*Y[2t+1] ----------------
__global__ void combine_kernel(const float* __restrict__ Y,
                               const float* __restrict__ ew,
                               float* __restrict__ out)
{
  int idx = blockIdx.x * 256 + threadIdx.x;
  int t = idx >> 9;
  int h = (idx & 511) * 4;
  float w0 = ew[2 * t], w1 = ew[2 * t + 1];
  float4 y0 = *(const float4*)&Y[(long)(2 * t) * HID + h];
  float4 y1 = *(const float4*)&Y[(long)(2 * t + 1) * HID + h];
  float4 o;
  o.x = w0 * y0.x + w1 * y1.x;
  o.y = w0 * y0.y + w1 * y1.y;
  o.z = w0 * y0.z + w1 * y1.z;
  o.w = w0 * y0.w + w1 * y1.w;
  *(float4*)&out[(long)t * HID + h] = o;
}

extern "C" void kernel_launch(void* const* d_in, const int* in_sizes, int n_in,
                              void* d_out, int out_size, void* d_ws, size_t ws_size,
                              hipStream_t stream) {
  const float* x   = (const float*)d_in[0];
  const int*   eix = (const int*)d_in[1];
  const float* ew  = (const float*)d_in[2];
  const float* w1  = (const float*)d_in[3];
  const float* w2  = (const float*)d_in[4];
  const float* w3  = (const float*)d_in[5];
  float* out = (float*)d_out;

  char* ws = (char*)d_ws;
  unsigned short* w1t = (unsigned short*)(ws + W1T_OFF);
  unsigned short* w3t = (unsigned short*)(ws + W3T_OFF);
  unsigned short* w2t = (unsigned short*)(ws + W2T_OFF);
  unsigned short* xb  = (unsigned short*)(ws + XB_OFF);
  unsigned short* gb  = (unsigned short*)(ws + GB_OFF);
  float*          y   = (float*)(ws + Y_OFF);
  int*            rows  = (int*)(ws + ROWS_OFF);
  int*            offs  = (int*)(ws + OFFS_OFF);
  int*            tiles = (int*)(ws + TILE_OFF);

  routing_kernel<<<1, 256, 0, stream>>>(eix, rows, offs, tiles);
  convert_x_kernel<<<4096, 256, 0, stream>>>(x, xb);
  transpose_convert_kernel<<<dim3(64, 64, 24), 256, 0, stream>>>(w1, w2, w3, w1t, w2t, w3t);
  gemm_gateup<<<dim3(INTER / 64, NTSLOTS), 256, 0, stream>>>(
      xb, w1t, w3t, gb, rows, offs, tiles);
  gemm_down<<<dim3(HID / 64, NTSLOTS), 256, 0, stream>>>(
      gb, w2t, y, rows, offs, tiles);
  combine_kernel<<<4096, 256, 0, stream>>>(y, ew, out);
}